// Round 8
// baseline (129.212 us; speedup 1.0000x reference)
//
#include <hip/hip_runtime.h>

typedef float __attribute__((ext_vector_type(4))) f32x4;

// OUT[n, c=j*8+k, h, w] = sum_{a,m,b} W[j,a,m,b,k] * T[n,(j+a-1)*4+m, (h-1)%28, (w+b-2)%28]
//   T[n,cc,h,w] = x[n,cc,h,w] + x[n,cc+128,h,w]
//   (j+a-1) outside [0,32) -> zero (channel pad); (w+b-1) outside [0,28) -> zero (w pad)
//
// R8: coalescing-first restructure. Block = (n, j): loads the 12 T-channels it needs as
//   WHOLE 784-float planes (wave-contiguous 1KB/instr), output rows stored contiguously.
//   R1/R2/R6/R7 all pinned at ~2.9 TB/s effective because lanes accessed 16B chunks
//   3136B apart (latency-starved: ~2KB in flight per CU vs ~25KB needed).
// LDS: Tl[12][28 rows x pitch 29] f32 = 39 KB -> 4 blocks/CU. Pitch 29: compute lanes
//   h=0..27 reading column w' hit banks (29h+w')%32, all distinct (gcd(29,32)=1);
//   duplicate k-groups read identical addresses -> broadcast. Conflict-free.
// Compute: thread t<224 = (k=t/28, h=t%28) produces OUT[n, j*8+k, h, :28] (1008 FMA,
//   336 scalar ds_reads with immediate offsets). Straight-line unrolled (no spill).
// x channels read 3x logically; x (103 MB) fits L3, per-n slab (800 KB) fits L2 ->
//   HBM fetch stays ~1x.

__global__ __launch_bounds__(256, 4) void fused_shift_conv(
    const float* __restrict__ x, const float* __restrict__ Wt, float* __restrict__ out)
{
    __shared__ float Tl[12 * 812];          // 12 channels x (28 rows * pitch 29), 39 KB

    const int blk = blockIdx.x;
    const int n   = blk >> 5;               // image
    const int j   = blk & 31;               // output channel group

    const int t = threadIdx.x;

    // ---- staging: 12 T-channel planes, wave-contiguous float4 loads ----
    // float4 index f = cl*196 + r over cl=0..11 channels, r=0..195 within plane
    const float* xn = x + (size_t)n * 200704;
    for (int f = t; f < 2352; f += 256) {
        const int cl  = f / 196;            // local channel 0..11
        const int r   = f - cl * 196;       // float4 within plane
        const int gch = j * 4 + cl - 4;     // global T channel
        f32x4 v = {0.f, 0.f, 0.f, 0.f};
        if (gch >= 0 && gch < 128) {
            const float* p = xn + gch * 784 + r * 4;
            const f32x4 lo = *(const f32x4*)p;
            const f32x4 hi = *(const f32x4*)(p + 100352);
            v = lo + hi;
        }
        // scatter 4 floats into pitch-29 rows (float4 can straddle a row boundary)
        #pragma unroll
        for (int e = 0; e < 4; ++e) {
            const int idx = r * 4 + e;      // 0..783 within plane
            const int hh  = idx / 28;
            const int ww  = idx - hh * 28;
            Tl[cl * 812 + hh * 29 + ww] = v[e];
        }
    }

    // ---- per-thread weights: thread t -> (k = t/28, h = t%28), channel c = j*8+k ----
    const int k = t / 28;                   // 0..7 (t<224), garbage for t>=224 (masked)
    const int h = t - k * 28;
    float wr[3][4][3];
    {
        const float* wp = Wt + j * 288 + (k & 7);   // W[j,a,m,b,k] strides 288/96/24/8/1
        #pragma unroll
        for (int a = 0; a < 3; ++a)
            #pragma unroll
            for (int m = 0; m < 4; ++m)
                #pragma unroll
                for (int bb = 0; bb < 3; ++bb)
                    wr[a][m][bb] = wp[a * 96 + m * 24 + bb * 8];
    }
    // OOB channel groups: LDS planes are zero-filled, weights left as-is is fine, but
    // zero them anyway to keep the R2-verified structure (0 * 0 = 0).
    if (j == 0) {
        #pragma unroll
        for (int m = 0; m < 4; ++m)
            #pragma unroll
            for (int bb = 0; bb < 3; ++bb) wr[0][m][bb] = 0.f;
    }
    if (j == 31) {
        #pragma unroll
        for (int m = 0; m < 4; ++m)
            #pragma unroll
            for (int bb = 0; bb < 3; ++bb) wr[2][m][bb] = 0.f;
    }

    __syncthreads();

    if (t < 224) {
        const int h_src = (h + 27) % 28;    // roll(+1) along h

        float acc[28];
        #pragma unroll
        for (int w = 0; w < 28; ++w) acc[w] = 0.f;

        #pragma unroll
        for (int a = 0; a < 3; ++a) {
            #pragma unroll
            for (int m = 0; m < 4; ++m) {
                const int rowb = (a * 4 + m) * 812 + h_src * 29;
                const float w2 = wr[a][m][2];
                const float w1 = wr[a][m][1];
                const float w0 = wr[a][m][0];
                #pragma unroll
                for (int wp_ = 0; wp_ < 28; ++wp_) {
                    const float v = Tl[rowb + wp_];
                    if (wp_ != 27) acc[wp_] += v * w2;               // b=2 tap
                    acc[(wp_ + 1) % 28] += v * w1;                   // b=1 tap
                    if (wp_ != 26) acc[(wp_ + 2) % 28] += v * w0;    // b=0 tap
                }
            }
        }

        // ---- write OUT[n, j*8+k, h, 0..27]: 7 float4, contiguous within k-group ----
        float* op = out + (size_t)n * 200704 + (size_t)(j * 8 + k) * 784 + h * 28;
        #pragma unroll
        for (int q = 0; q < 7; ++q) {
            f32x4 o;
            o.x = acc[q * 4 + 0];
            o.y = acc[q * 4 + 1];
            o.z = acc[q * 4 + 2];
            o.w = acc[q * 4 + 3];
            *(f32x4*)(op + q * 4) = o;
        }
    }
}

extern "C" void kernel_launch(void* const* d_in, const int* in_sizes, int n_in,
                              void* d_out, int out_size, void* d_ws, size_t ws_size,
                              hipStream_t stream) {
    const float* x  = (const float*)d_in[0];   // (128,256,28,28) f32
    const float* Wt = (const float*)d_in[1];   // (32,3,4,3,8)   f32
    float* out      = (float*)d_out;           // (128,256,28,28) f32

    const int nbatch = in_sizes[0] / 200704;   // 128
    fused_shift_conv<<<nbatch * 32, 256, 0, stream>>>(x, Wt, out);
}

// Round 9
// 70.344 us; speedup vs baseline: 1.8369x; 1.8369x over previous
//
#include <hip/hip_runtime.h>

typedef float __attribute__((ext_vector_type(4))) f32x4;
typedef unsigned int u32;
typedef u32 __attribute__((ext_vector_type(4))) u32x4;

// OUT[n, c=j*8+k, h, w] = sum_{a,m,b} W[j,a,m,b,k] * T[n,(j+a-1)*4+m, (h-1)%28, (w+b-2)%28]
//   T[n,cc,h,w] = x[n,cc,h,w] + x[n,cc+128,h,w]
//   (j+a-1) outside [0,32) -> zero (channel pad); (w+b-1) outside [0,28) -> zero (w pad)
//
// R9 = R7 with 4 rows fused per block for occupancy. R7 (68 us) had VALUBusy 21%, eff-BW
//   ~46%, occupancy 42% (~13 waves/CU): latency-bound with too few resident waves.
//   Here: 1024-thread blocks, slice = t>>8 owns one row with its own 8 KB LDS region ->
//   2 blocks/CU x 16 waves = 32 waves/CU potential, one barrier per 4 rows.
// Math/staging/swizzle identical to R7 (passed, absmax 0.5): bf16-pair LDS m-packing,
//   v_dot2_f32_bf16 f32-accumulate, quad-slot swizzle qb^(g&7) (R2-verified conflict-free),
//   pad slot duplicates quad 6 and is never read.

__device__ __forceinline__ u32 pack2bf(float lo, float hi) {
    u32 a = __float_as_uint(lo), b = __float_as_uint(hi);
    a = (a + 0x7FFFu + ((a >> 16) & 1u)) >> 16;   // RNE round to bf16
    b = (b + 0x7FFFu + ((b >> 16) & 1u)) >> 16;
    return a | (b << 16);
}

__device__ __forceinline__ float dot2bf(u32 t2, u32 w2, float acc) {
    asm("v_dot2_f32_bf16 %0, %1, %2, %0" : "+v"(acc) : "v"(t2), "v"(w2));
    return acc;
}

__global__ __launch_bounds__(1024, 8) void fused_shift_conv(
    const float* __restrict__ x, const float* __restrict__ Wt, float* __restrict__ out)
{
    __shared__ __align__(16) u32 B[4 * 2048];   // 4 slices x (64 rows x 32 dwords) = 32 KB

    const int tid   = threadIdx.x;
    const int slice = tid >> 8;             // 0..3: which row this slice handles
    const int t     = tid & 255;            // thread within slice
    u32* Bs = B + slice * 2048;

    const int R = blockIdx.x * 4 + slice;   // global row index n*28 + h
    const int n = R / 28;
    const int h = R - n * 28;
    const int h_src = (h + 27) % 28;        // roll(+1) along h

    // ---- staging: thread t fills LDS row rr = t>>2 (ch pair), quads qA, qA+1 ----
    const int rr = t >> 2;                  // 0..63
    const int gs = rr >> 1;                 // group 0..31
    const int mp = rr & 1;                  // m-pair 0/1
    const int ch0 = gs * 4 + mp * 2;
    const int qA  = (t & 3) * 2;            // 0,2,4,6
    const int qBr = qA + 1;                 // 1,3,5,7
    const int qB  = (qBr > 6) ? 6 : qBr;    // clamp: pad slot gets dup of quad 6
    const int sw  = gs & 7;
    const int dA  = rr * 32 + (qA ^ sw) * 4;   // dword index of b128 write A
    const int dB  = rr * 32 + (qBr ^ sw) * 4;  // pad slot (7^sw) never read

    const float* base = x + (size_t)n * 200704 + h_src * 28;
    const float* pA = base + ch0 * 784 + qA * 4;
    const float* pB = base + ch0 * 784 + qB * 4;

    const f32x4 l0A = *(const f32x4*)pA;
    const f32x4 h0A = *(const f32x4*)(pA + 100352);
    const f32x4 l1A = *(const f32x4*)(pA + 784);
    const f32x4 h1A = *(const f32x4*)(pA + 784 + 100352);
    const f32x4 l0B = *(const f32x4*)pB;
    const f32x4 h0B = *(const f32x4*)(pB + 100352);
    const f32x4 l1B = *(const f32x4*)(pB + 784);
    const f32x4 h1B = *(const f32x4*)(pB + 784 + 100352);

    const f32x4 s0A = l0A + h0A, s1A = l1A + h1A;
    const f32x4 s0B = l0B + h0B, s1B = l1B + h1B;
    u32x4 wvA, wvB;
    #pragma unroll
    for (int e = 0; e < 4; ++e) {
        wvA[e] = pack2bf(s0A[e], s1A[e]);   // low = ch 4g+2mp, high = ch 4g+2mp+1
        wvB[e] = pack2bf(s0B[e], s1B[e]);
    }
    *(u32x4*)&Bs[dA] = wvA;
    *(u32x4*)&Bs[dB] = wvB;

    // ---- per-thread weights, bf16-pair packed along m: thread t owns c = j*8+k ----
    const int j = t >> 3, k = t & 7;
    u32 w2[3][2][3];                        // [a][m-pair][tap]
    {
        const float* wp = Wt + j * 288 + k; // W[j,a,m,b,k] strides 288/96/24/8/1
        #pragma unroll
        for (int a = 0; a < 3; ++a)
            #pragma unroll
            for (int m2 = 0; m2 < 2; ++m2)
                #pragma unroll
                for (int bb = 0; bb < 3; ++bb)
                    w2[a][m2][bb] = pack2bf(wp[a*96 + (2*m2  )*24 + bb*8],
                                            wp[a*96 + (2*m2+1)*24 + bb*8]);
    }
    if (j == 0) {
        #pragma unroll
        for (int m2 = 0; m2 < 2; ++m2)
            #pragma unroll
            for (int bb = 0; bb < 3; ++bb) w2[0][m2][bb] = 0u;
    }
    if (j == 31) {
        #pragma unroll
        for (int m2 = 0; m2 < 2; ++m2)
            #pragma unroll
            for (int bb = 0; bb < 3; ++bb) w2[2][m2][bb] = 0u;
    }

    __syncthreads();

    // ---- compute: 42 ds_read_b128 + ~492 v_dot2_f32_bf16 per thread ----
    float acc[28];
    #pragma unroll
    for (int w = 0; w < 28; ++w) acc[w] = 0.f;

    #pragma unroll
    for (int a = 0; a < 3; ++a) {
        int g = j + a - 1;
        g = g < 0 ? 0 : (g > 31 ? 31 : g);  // weights already zeroed for OOB
        const int s = g & 7;
        #pragma unroll
        for (int m2 = 0; m2 < 2; ++m2) {
            const int rowd = (g * 2 + m2) * 32;
            const u32 t2 = w2[a][m2][2], t1 = w2[a][m2][1], t0 = w2[a][m2][0];
            #pragma unroll
            for (int qb = 0; qb < 7; ++qb) {
                const u32x4 v = *(const u32x4*)&Bs[rowd + ((qb ^ s) << 2)];
                #pragma unroll
                for (int e = 0; e < 4; ++e) {
                    const int wp_ = qb * 4 + e;                              // source col w'
                    if (wp_ != 27) acc[wp_] = dot2bf(v[e], t2, acc[wp_]);    // b=2 tap
                    acc[(wp_ + 1) % 28] = dot2bf(v[e], t1, acc[(wp_ + 1) % 28]); // b=1
                    if (wp_ != 26) acc[(wp_ + 2) % 28] = dot2bf(v[e], t0, acc[(wp_ + 2) % 28]); // b=0
                }
            }
        }
    }

    // ---- write OUT[n, t, h, 0..27]: 7 aligned float4 stores ----
    float* op = out + (size_t)n * 200704 + (size_t)t * 784 + (size_t)h * 28;
    #pragma unroll
    for (int qq = 0; qq < 7; ++qq) {
        f32x4 o;
        o.x = acc[qq * 4 + 0];
        o.y = acc[qq * 4 + 1];
        o.z = acc[qq * 4 + 2];
        o.w = acc[qq * 4 + 3];
        *(f32x4*)(op + qq * 4) = o;
    }
}

extern "C" void kernel_launch(void* const* d_in, const int* in_sizes, int n_in,
                              void* d_out, int out_size, void* d_ws, size_t ws_size,
                              hipStream_t stream) {
    const float* x  = (const float*)d_in[0];   // (128,256,28,28) f32
    const float* Wt = (const float*)d_in[1];   // (32,3,4,3,8)   f32
    float* out      = (float*)d_out;           // (128,256,28,28) f32

    const int nbatch = in_sizes[0] / 200704;   // 128
    fused_shift_conv<<<nbatch * 7, 1024, 0, stream>>>(x, Wt, out);   // 4 rows per block
}

// Round 10
// 54.085 us; speedup vs baseline: 2.3890x; 1.3006x over previous
//
#include <hip/hip_runtime.h>

typedef float __attribute__((ext_vector_type(4))) f32x4;
typedef unsigned int u32;
typedef u32 __attribute__((ext_vector_type(4))) u32x4;

// OUT[n, c=j*8+k, h, w] = sum_{a,m,b} W[j,a,m,b,k] * T[n,(j+a-1)*4+m, (h-1)%28, (w+b-2)%28]
//   T[n,cc,h,w] = x[n,cc,h,w] + x[n,cc+128,h,w]
//   (j+a-1) outside [0,32) -> zero; (w+b-1) outside [0,28) -> zero (w unfold pad)
//
// R10: vmem-request-rate attack. R9 proved occupancy isn't the wall (42->63%, dur flat):
//   every round so far moved 16 B/lane at 3136 B stride (1-2 lanes per 64B line ->
//   ~10M line-requests/kernel saturating the L1/TA pipes at ~3 TB/s effective).
//   Fix both sides:
//   - input: cooperative staging, consecutive lanes cover (q,row) within a channel ->
//     448 B contiguous runs -> ~4 lanes/line  (loads: 3.2M -> 1.6M line-requests)
//   - output: stores routed through LDS; 4 rounds of 64 channels write acc into a
//     padded f32 buffer (reusing the input LDS), then contiguous stores of 448 B
//     per channel -> 4 lanes/line  (stores: 7.2M -> 1.8M line-requests)
// Block = (n, h-quad): 1024 threads = 4 slices x 256; slice s computes output row
//   h = 4*b4 + s (never wraps; only the INPUT row h_src = h-1 wraps, handled per-lane).
// Compute per slice: R7/R9-verified bf16-pair dot2 path (absmax 0.5), swizzle
//   slot = q ^ (g&7) (R2-verified conflict-free), pad slot never read.
// LDS: input bf16 [4][64 pairs][32 dwords] = 32 KB, reused after compute as the
//   f32 out-chunk buffer [64 ch][116] = 29.7 KB. 2 blocks/CU -> 32 waves/CU.

__device__ __forceinline__ u32 pack2bf(float lo, float hi) {
    u32 a = __float_as_uint(lo), b = __float_as_uint(hi);
    a = (a + 0x7FFFu + ((a >> 16) & 1u)) >> 16;   // RNE round to bf16
    b = (b + 0x7FFFu + ((b >> 16) & 1u)) >> 16;
    return a | (b << 16);
}

__device__ __forceinline__ float dot2bf(u32 t2, u32 w2, float acc) {
    asm("v_dot2_f32_bf16 %0, %1, %2, %0" : "+v"(acc) : "v"(t2), "v"(w2));
    return acc;
}

__global__ __launch_bounds__(1024, 8) void fused_shift_conv(
    const float* __restrict__ x, const float* __restrict__ Wt, float* __restrict__ out)
{
    __shared__ __align__(16) u32 L[8192];   // 32 KB; input bf16, later out f32 chunk

    const int tid = threadIdx.x;
    const int blk = blockIdx.x;
    const int n   = blk / 7;
    const int b4  = blk - n * 7;
    const int h0  = b4 * 4;                 // output rows h0..h0+3 (no wrap)

    const float* xn = x + (size_t)n * 200704;

    // ---- cooperative input staging: 64 pairs x 4 rows x 7 quads = 1792 items ----
    // consecutive lanes -> consecutive (q,row) within a channel pair: 448 B runs.
    #pragma unroll
    for (int rd = 0; rd < 2; ++rd) {
        const int f = tid + rd * 1024;
        if (f < 1792) {
            const int p   = f / 28;         // channel pair 0..63 (ch 2p, 2p+1)
            const int rem = f - p * 28;
            const int row = rem / 7;        // slice 0..3
            const int q   = rem - row * 7;  // quad 0..6
            int hs = h0 - 1 + row;          // input row; wraps only when h0==0,row==0
            hs = hs < 0 ? 27 : hs;
            const float* b0 = xn + (2 * p) * 784 + hs * 28 + q * 4;
            const f32x4 l0 = *(const f32x4*)b0;              // ch 2p,   low half
            const f32x4 l1 = *(const f32x4*)(b0 + 784);      // ch 2p+1, low half
            const f32x4 u0 = *(const f32x4*)(b0 + 100352);   // ch 2p,   high half
            const f32x4 u1 = *(const f32x4*)(b0 + 784 + 100352);
            const f32x4 s0 = l0 + u0, s1 = l1 + u1;
            u32x4 wv;
            #pragma unroll
            for (int e = 0; e < 4; ++e) wv[e] = pack2bf(s0[e], s1[e]);
            const int sw = (p >> 1) & 7;    // group swizzle (g = p>>1)
            *(u32x4*)&L[row * 2048 + p * 32 + (((q ^ sw)) << 2)] = wv;
        }
    }

    // ---- per-thread weights: slice-local thread t owns channel c = j*8+k ----
    const int t  = tid & 255;
    const int s_ = tid >> 8;                // slice = output row offset
    const int j = t >> 3, k = t & 7;
    u32 w2[3][2][3];                        // [a][m-pair][tap], bf16-pair packed
    {
        const float* wp = Wt + j * 288 + k; // W[j,a,m,b,k] strides 288/96/24/8/1
        #pragma unroll
        for (int a = 0; a < 3; ++a)
            #pragma unroll
            for (int m2 = 0; m2 < 2; ++m2)
                #pragma unroll
                for (int bb = 0; bb < 3; ++bb)
                    w2[a][m2][bb] = pack2bf(wp[a*96 + (2*m2  )*24 + bb*8],
                                            wp[a*96 + (2*m2+1)*24 + bb*8]);
    }
    if (j == 0) {
        #pragma unroll
        for (int m2 = 0; m2 < 2; ++m2)
            #pragma unroll
            for (int bb = 0; bb < 3; ++bb) w2[0][m2][bb] = 0u;
    }
    if (j == 31) {
        #pragma unroll
        for (int m2 = 0; m2 < 2; ++m2)
            #pragma unroll
            for (int bb = 0; bb < 3; ++bb) w2[2][m2][bb] = 0u;
    }

    __syncthreads();

    // ---- compute (R9 body): 42 ds_read_b128 + ~492 dot2 per thread ----
    const u32* Bs = L + s_ * 2048;
    float acc[28];
    #pragma unroll
    for (int w = 0; w < 28; ++w) acc[w] = 0.f;

    #pragma unroll
    for (int a = 0; a < 3; ++a) {
        int g = j + a - 1;
        g = g < 0 ? 0 : (g > 31 ? 31 : g);  // weights already zeroed for OOB
        const int s = g & 7;
        #pragma unroll
        for (int m2 = 0; m2 < 2; ++m2) {
            const int rowd = (g * 2 + m2) * 32;
            const u32 t2 = w2[a][m2][2], t1 = w2[a][m2][1], t0 = w2[a][m2][0];
            #pragma unroll
            for (int qb = 0; qb < 7; ++qb) {
                const u32x4 v = *(const u32x4*)&Bs[rowd + ((qb ^ s) << 2)];
                #pragma unroll
                for (int e = 0; e < 4; ++e) {
                    const int wp_ = qb * 4 + e;                              // source col w'
                    if (wp_ != 27) acc[wp_] = dot2bf(v[e], t2, acc[wp_]);    // b=2 tap
                    acc[(wp_ + 1) % 28] = dot2bf(v[e], t1, acc[(wp_ + 1) % 28]); // b=1
                    if (wp_ != 26) acc[(wp_ + 2) % 28] = dot2bf(v[e], t0, acc[(wp_ + 2) % 28]); // b=0
                }
            }
        }
    }

    // ---- output via LDS: 4 rounds of 64 channels, contiguous 448 B stores ----
    float* Lf = (float*)L;                  // reuse input buffer (29.7 KB needed)
    float* outn = out + (size_t)n * 200704;
    #pragma unroll
    for (int c = 0; c < 4; ++c) {
        __syncthreads();                    // compute done / prev round's reads done
        if ((j >> 3) == c) {
            const int oc = (j & 7) * 8 + k; // local channel 0..63
            float* dst = Lf + oc * 116 + s_ * 28;   // pitch 116 floats (16B-aligned)
            #pragma unroll
            for (int qq = 0; qq < 7; ++qq) {
                f32x4 o;
                o.x = acc[qq * 4 + 0];
                o.y = acc[qq * 4 + 1];
                o.z = acc[qq * 4 + 2];
                o.w = acc[qq * 4 + 3];
                *(f32x4*)(dst + qq * 4) = o;
            }
        }
        __syncthreads();
        #pragma unroll
        for (int rd = 0; rd < 2; ++rd) {
            const int fo = tid + rd * 1024;
            if (fo < 1792) {
                const int chl = fo / 28;            // local channel 0..63
                const int rem = fo - chl * 28;      // float4 within 448 B run
                const f32x4 v = *(const f32x4*)(Lf + chl * 116 + rem * 4);
                *(f32x4*)(outn + (size_t)(c * 64 + chl) * 784 + h0 * 28 + rem * 4) = v;
            }
        }
    }
}

extern "C" void kernel_launch(void* const* d_in, const int* in_sizes, int n_in,
                              void* d_out, int out_size, void* d_ws, size_t ws_size,
                              hipStream_t stream) {
    const float* x  = (const float*)d_in[0];   // (128,256,28,28) f32
    const float* Wt = (const float*)d_in[1];   // (32,3,4,3,8)   f32
    float* out      = (float*)d_out;           // (128,256,28,28) f32

    const int nbatch = in_sizes[0] / 200704;   // 128
    fused_shift_conv<<<nbatch * 7, 1024, 0, stream>>>(x, Wt, out);   // (n, h-quad)
}

// Round 11
// 50.313 us; speedup vs baseline: 2.5682x; 1.0750x over previous
//
#include <hip/hip_runtime.h>

typedef float __attribute__((ext_vector_type(4))) f32x4;
typedef unsigned int u32;
typedef u32 __attribute__((ext_vector_type(4))) u32x4;

// OUT[n, c=j*8+k, h, w] = sum_{a,m,b} W[j,a,m,b,k] * T[n,(j+a-1)*4+m, (h-1)%28, (w+b-2)%28]
//   T[n,cc,h,w] = x[n,cc,h,w] + x[n,cc+128,h,w]
//   (j+a-1) outside [0,32) -> zero; (w+b-1) outside [0,28) -> zero (w unfold pad)
//
// R11 = R10 with 4 blocks/CU for phase overlap. R10 (54 us) had no pipe >50% busy with
//   only 2 resident 16-wave blocks: phase bubbles (stage/compute/9-barrier out tail)
//   couldn't overlap. Here: 512-thread blocks (2 rows), 30.7 KB LDS -> 4 blocks/CU,
//   output in 2 rounds of 128 ch (5 barriers/block), round-invariant indices hoisted.
// Verified pieces kept byte-for-byte: bf16-pair m-packed LDS + v_dot2_f32_bf16 compute
//   (absmax 0.5, R7/R9/R10), quad-slot swizzle q^(g&7) (R2: 0 conflicts), coalesced
//   224B-run staging loads and LDS-routed 224B-run output stores (R10: WRITE == 100 MB).

__device__ __forceinline__ u32 pack2bf(float lo, float hi) {
    u32 a = __float_as_uint(lo), b = __float_as_uint(hi);
    a = (a + 0x7FFFu + ((a >> 16) & 1u)) >> 16;   // RNE round to bf16
    b = (b + 0x7FFFu + ((b >> 16) & 1u)) >> 16;
    return a | (b << 16);
}

__device__ __forceinline__ float dot2bf(u32 t2, u32 w2, float acc) {
    asm("v_dot2_f32_bf16 %0, %1, %2, %0" : "+v"(acc) : "v"(t2), "v"(w2));
    return acc;
}

__global__ __launch_bounds__(512, 8) void fused_shift_conv(
    const float* __restrict__ x, const float* __restrict__ Wt, float* __restrict__ out)
{
    // input: 2 rows x 2048 dwords (16 KB, first 4096 dwords)
    // output rounds reuse the whole buffer: 128 ch x 60 floats = 30.7 KB
    __shared__ __align__(16) u32 L[7680];

    const int tid = threadIdx.x;
    const int blk = blockIdx.x;
    const int n   = blk / 14;
    const int b2  = blk - n * 14;
    const int h0  = b2 * 2;                 // output rows h0, h0+1 (no wrap; 2*13+1=27)

    const float* xn = x + (size_t)n * 200704;

    // ---- staging: 64 ch-pairs x 2 input rows x 7 quads = 896 items ----
    // consecutive items walk (row,q) within a pair -> 224 B contiguous runs.
    #pragma unroll
    for (int it = 0; it < 2; ++it) {
        const int f = tid + it * 512;
        if (f < 896) {
            const int p     = f / 14;       // channel pair 0..63 (ch 2p, 2p+1)
            const int rem14 = f - p * 14;
            const int row   = rem14 / 7;    // input row index 0..1
            const int q     = rem14 - row * 7;
            int hs = h0 - 1 + row;          // wraps only when h0==0 && row==0
            hs = hs < 0 ? 27 : hs;
            const float* b0 = xn + (2 * p) * 784 + hs * 28 + q * 4;
            const f32x4 l0 = *(const f32x4*)b0;                  // ch 2p,   low half
            const f32x4 l1 = *(const f32x4*)(b0 + 784);          // ch 2p+1, low half
            const f32x4 u0 = *(const f32x4*)(b0 + 100352);       // high halves
            const f32x4 u1 = *(const f32x4*)(b0 + 784 + 100352);
            const f32x4 s0 = l0 + u0, s1 = l1 + u1;
            u32x4 wv;
            #pragma unroll
            for (int e = 0; e < 4; ++e) wv[e] = pack2bf(s0[e], s1[e]);
            const int sw = (p >> 1) & 7;    // g = p>>1
            *(u32x4*)&L[row * 2048 + p * 32 + ((q ^ sw) << 2)] = wv;
        }
    }

    // ---- per-thread weights: slice s_ computes row h0+s_, thread owns c = j*8+k ----
    const int t  = tid & 255;
    const int s_ = tid >> 8;                // slice 0/1
    const int j = t >> 3, k = t & 7;
    u32 w2[3][2][3];                        // [a][m-pair][tap], bf16-pair packed
    {
        const float* wp = Wt + j * 288 + k; // W[j,a,m,b,k] strides 288/96/24/8/1
        #pragma unroll
        for (int a = 0; a < 3; ++a)
            #pragma unroll
            for (int m2 = 0; m2 < 2; ++m2)
                #pragma unroll
                for (int bb = 0; bb < 3; ++bb)
                    w2[a][m2][bb] = pack2bf(wp[a*96 + (2*m2  )*24 + bb*8],
                                            wp[a*96 + (2*m2+1)*24 + bb*8]);
    }
    if (j == 0) {
        #pragma unroll
        for (int m2 = 0; m2 < 2; ++m2)
            #pragma unroll
            for (int bb = 0; bb < 3; ++bb) w2[0][m2][bb] = 0u;
    }
    if (j == 31) {
        #pragma unroll
        for (int m2 = 0; m2 < 2; ++m2)
            #pragma unroll
            for (int bb = 0; bb < 3; ++bb) w2[2][m2][bb] = 0u;
    }

    // ---- hoisted output-stage indices (round-invariant) ----
    // round: 128 local ch x 2 rows x 7 quads = 1792 f4 items; 4 iterations of 512
    int o_lds[4], o_glb[4];                 // LDS dword offset, global float offset
    #pragma unroll
    for (int it = 0; it < 4; ++it) {
        const int fo  = tid + it * 512;
        const int chl = fo / 14;            // local channel 0..127 (fo<1792)
        const int rem = fo - chl * 14;      // f4 within the 56-float (2-row) run
        o_lds[it] = chl * 60 + rem * 4;
        o_glb[it] = chl * 784 + h0 * 28 + rem * 4;
    }

    __syncthreads();

    // ---- compute (R10 body, verified): 42 ds_read_b128 + ~492 dot2 ----
    const u32* Bs = L + s_ * 2048;
    float acc[28];
    #pragma unroll
    for (int w = 0; w < 28; ++w) acc[w] = 0.f;

    #pragma unroll
    for (int a = 0; a < 3; ++a) {
        int g = j + a - 1;
        g = g < 0 ? 0 : (g > 31 ? 31 : g);  // weights already zeroed for OOB
        const int s = g & 7;
        #pragma unroll
        for (int m2 = 0; m2 < 2; ++m2) {
            const int rowd = (g * 2 + m2) * 32;
            const u32 t2 = w2[a][m2][2], t1 = w2[a][m2][1], t0 = w2[a][m2][0];
            #pragma unroll
            for (int qb = 0; qb < 7; ++qb) {
                const u32x4 v = *(const u32x4*)&Bs[rowd + ((qb ^ s) << 2)];
                #pragma unroll
                for (int e = 0; e < 4; ++e) {
                    const int wp_ = qb * 4 + e;                              // source col w'
                    if (wp_ != 27) acc[wp_] = dot2bf(v[e], t2, acc[wp_]);    // b=2 tap
                    acc[(wp_ + 1) % 28] = dot2bf(v[e], t1, acc[(wp_ + 1) % 28]); // b=1
                    if (wp_ != 26) acc[(wp_ + 2) % 28] = dot2bf(v[e], t0, acc[(wp_ + 2) % 28]); // b=0
                }
            }
        }
    }

    // ---- output: 2 rounds of 128 channels via LDS, contiguous 224 B stores ----
    float* Lf = (float*)L;                  // input region dead after compute
    float* outn = out + (size_t)n * 200704;
    #pragma unroll
    for (int c = 0; c < 2; ++c) {
        __syncthreads();                    // compute done / prev round reads done
        if ((j >> 4) == c) {
            const int oc = (j & 15) * 8 + k;         // local channel 0..127
            float* dst = Lf + oc * 60 + s_ * 28;     // pitch 60 floats, 16B-aligned
            #pragma unroll
            for (int qq = 0; qq < 7; ++qq) {
                f32x4 o;
                o.x = acc[qq * 4 + 0];
                o.y = acc[qq * 4 + 1];
                o.z = acc[qq * 4 + 2];
                o.w = acc[qq * 4 + 3];
                *(f32x4*)(dst + qq * 4) = o;
            }
        }
        __syncthreads();
        float* outc = outn + (size_t)c * 128 * 784;
        #pragma unroll
        for (int it = 0; it < 4; ++it) {
            if (tid + it * 512 < 1792) {
                const f32x4 v = *(const f32x4*)(Lf + o_lds[it]);
                *(f32x4*)(outc + o_glb[it]) = v;
            }
        }
    }
}

extern "C" void kernel_launch(void* const* d_in, const int* in_sizes, int n_in,
                              void* d_out, int out_size, void* d_ws, size_t ws_size,
                              hipStream_t stream) {
    const float* x  = (const float*)d_in[0];   // (128,256,28,28) f32
    const float* Wt = (const float*)d_in[1];   // (32,3,4,3,8)   f32
    float* out      = (float*)d_out;           // (128,256,28,28) f32

    const int nbatch = in_sizes[0] / 200704;   // 128
    fused_shift_conv<<<nbatch * 14, 512, 0, stream>>>(x, Wt, out);  // (n, h-pair)
}